// Round 4
// baseline (265.349 us; speedup 1.0000x reference)
//
#include <hip/hip_runtime.h>
#include <hip/hip_bf16.h>
#include <math.h>

// ---------------------------------------------------------------------------
// TimeAttender: S=2048, B=32, D=512, K=147
// out = concat(applied [B*D], norm_w [B*S])
//
// Math notes:
//  * prev_probs normalizer and softmax Z cancel:
//      norm_w = adj * exp(w) / sum_s(adj * exp(w))
//  * w = cosine similarity in [-1,1] -> exp(w) in [0.37, 2.72]: no max
//    subtraction needed -> single-pass over e (read exactly once).
//  * main_kernel lane layout: 16 lanes per s-row x 4 rows per wave, so all
//    per-row reductions use shfl_xor offsets {1,2,4,8} (DPP, VALU pipe) --
//    no ds_bpermute on the per-row critical path.
// ---------------------------------------------------------------------------

__device__ __forceinline__ float group16_sum(float v) {
    v += __shfl_xor(v, 1);
    v += __shfl_xor(v, 2);
    v += __shfl_xor(v, 4);
    v += __shfl_xor(v, 8);
    return v;
}
__device__ __forceinline__ float wave_sum(float v) {
    for (int off = 32; off; off >>= 1) v += __shfl_xor(v, off);
    return v;
}

// ---------------------------------------------------------------------------
// K1: grid (1 + S/512, B), block 512.
//   bx == 0 : ns[b,:] = normalize(state[b,:] @ W^T + bias)
//   bx >= 1 : adj[b,s] = relu(conv1d_same(prev[b,:], cw)[s] + cb0), 512 s each
// ---------------------------------------------------------------------------
__global__ __launch_bounds__(512) void front_kernel(
    const float* __restrict__ state, const float* __restrict__ W,
    const float* __restrict__ bias, const float* __restrict__ prev,
    const float* __restrict__ cw, const float* __restrict__ cb,
    float* __restrict__ ns, float* __restrict__ adj,
    int S, int D, int K) {
    __shared__ __align__(16) float smem[824];
    int b = blockIdx.y;
    int t = threadIdx.x;

    if (blockIdx.x == 0) {
        // ---- linear + row-normalize ----
        if (t < D / 4)
            ((float4*)smem)[t] = ((const float4*)(state + (size_t)b * D))[t];
        __syncthreads();
        const float4* Wrow = (const float4*)(W + (size_t)t * D);
        const float4* sv = (const float4*)smem;
        float acc = bias[t];
#pragma unroll 8
        for (int k = 0; k < 128; ++k) {
            float4 w4 = Wrow[k];
            float4 s4 = sv[k];
            acc += w4.x * s4.x + w4.y * s4.y + w4.z * s4.z + w4.w * s4.w;
        }
        // block reduction of acc^2 across 8 waves
        float sq = wave_sum(acc * acc);
        __shared__ float red[8];
        int lane = t & 63, wv = t >> 6;
        if (lane == 0) red[wv] = sq;
        __syncthreads();
        float total = red[0] + red[1] + red[2] + red[3]
                    + red[4] + red[5] + red[6] + red[7];
        float inv = (total == 0.f) ? 0.f : rsqrtf(total);
        ns[(size_t)b * D + t] = acc * inv;
    } else {
        // ---- conv + relu (unnormalized) ----
        int s0 = (blockIdx.x - 1) * 512;
        int pad = K / 2;
        int seglen = 512 + K - 1;            // 658
        float* seg = smem;                   // [658]
        float* wk = smem + 664;              // [147]
        for (int i = t; i < seglen; i += 512) {
            int s = s0 - pad + i;
            seg[i] = (s >= 0 && s < S) ? prev[(size_t)b * S + s] : 0.f;
        }
        for (int j = t; j < K; j += 512) wk[j] = cw[j];
        __syncthreads();
        float y = cb[0];
        for (int j = 0; j < K; ++j) y += seg[t + j] * wk[j];
        adj[(size_t)b * S + s0 + t] = fmaxf(y, 0.f);
    }
}

// ---------------------------------------------------------------------------
// K2 (single e pass): grid (NCB/4, B), block 256 = 4 waves.
// Wave owns chunk of CH=16 rows, processed as 4 groups of 4 rows.
// lane = r*16 + c: r = row within group, c = d-slice (float4 idx c+16j).
// ---------------------------------------------------------------------------
__global__ __launch_bounds__(256) void main_kernel(
    const float* __restrict__ e, const float* __restrict__ ns,
    const float* __restrict__ adj, float* __restrict__ partial,
    float* __restrict__ zbuf, float* __restrict__ u,
    int S, int B, int D, int CH) {
    int wave = threadIdx.x >> 6;
    int lane = threadIdx.x & 63;
    int r = lane >> 4;
    int c = lane & 15;
    int chunk = blockIdx.x * 4 + wave;
    int b = blockIdx.y;
    int s0 = chunk * CH;

    // ns slices for this lane: float4 indices c+16j
    const float4* ns4 = (const float4*)(ns + (size_t)b * D);
    float4 nsv[8];
#pragma unroll
    for (int j = 0; j < 8; ++j) nsv[j] = ns4[c + 16 * j];

    float4 acc[8];
#pragma unroll
    for (int j = 0; j < 8; ++j) acc[j] = make_float4(0.f, 0.f, 0.f, 0.f);
    float z = 0.f;

    size_t rowstride = (size_t)B * D / 4;  // float4 stride between s rows
    const float4* base = (const float4*)(e + ((size_t)(s0 + r) * B + b) * D);
    const float* arow = adj + (size_t)b * S + s0;
    float* urow = u + (size_t)b * S + s0;

    for (int g = 0; g < 4; ++g) {
        const float4* rp = base + (size_t)(4 * g) * rowstride;
        float4 x[8];
#pragma unroll
        for (int j = 0; j < 8; ++j) x[j] = rp[c + 16 * j];
        float dot = 0.f, sq = 0.f;
#pragma unroll
        for (int j = 0; j < 8; ++j) {
            dot += x[j].x * nsv[j].x + x[j].y * nsv[j].y
                 + x[j].z * nsv[j].z + x[j].w * nsv[j].w;
            sq  += x[j].x * x[j].x + x[j].y * x[j].y
                 + x[j].z * x[j].z + x[j].w * x[j].w;
        }
        dot = group16_sum(dot);
        sq  = group16_sum(sq);
        float winv = (sq == 0.f) ? 0.f : rsqrtf(sq);
        float w = dot * winv;
        float coef = arow[4 * g + r] * __expf(w);
        if (c == 0) urow[4 * g + r] = coef;
        z += coef;
#pragma unroll
        for (int j = 0; j < 8; ++j) {
            acc[j].x += coef * x[j].x; acc[j].y += coef * x[j].y;
            acc[j].z += coef * x[j].z; acc[j].w += coef * x[j].w;
        }
    }

    // cross-r combine (once per chunk): offsets 16, 32
#pragma unroll
    for (int j = 0; j < 8; ++j) {
        acc[j].x += __shfl_xor(acc[j].x, 16);
        acc[j].y += __shfl_xor(acc[j].y, 16);
        acc[j].z += __shfl_xor(acc[j].z, 16);
        acc[j].w += __shfl_xor(acc[j].w, 16);
        acc[j].x += __shfl_xor(acc[j].x, 32);
        acc[j].y += __shfl_xor(acc[j].y, 32);
        acc[j].z += __shfl_xor(acc[j].z, 32);
        acc[j].w += __shfl_xor(acc[j].w, 32);
    }
    z += __shfl_xor(z, 16);
    z += __shfl_xor(z, 32);

    float4* p4 = (float4*)(partial + ((size_t)chunk * B + b) * D);
    if (r == 0) {
#pragma unroll
        for (int j = 0; j < 8; ++j) p4[c + 16 * j] = acc[j];
    }
    if (lane == 0) zbuf[(size_t)chunk * B + b] = z;
}

// ---------------------------------------------------------------------------
// K3: grid B, block 256.
//   Z = sum_c zbuf[c][b]; applied[b,:] = sum_c partial[c][b][:] / Z;
//   norm_w[b,s] = u[b,s] / Z
// ---------------------------------------------------------------------------
__global__ __launch_bounds__(256) void combine_kernel(
    const float* __restrict__ partial, const float* __restrict__ zbuf,
    const float* __restrict__ u, float* __restrict__ applied,
    float* __restrict__ norm_w, int S, int B, int D, int NCB) {
    int b = blockIdx.x;
    int t = threadIdx.x;
    int lane = t & 63, wv = t >> 6;
    __shared__ float red[4];
    __shared__ float zsh;

    float zt = (t < NCB) ? zbuf[(size_t)t * B + b] : 0.f;
    zt = wave_sum(zt);
    if (lane == 0) red[wv] = zt;
    __syncthreads();
    if (t == 0) zsh = 1.f / (red[0] + red[1] + red[2] + red[3]);
    __syncthreads();
    float inv = zsh;

    if (t < D / 4) {
        float4 acc = {0.f, 0.f, 0.f, 0.f};
        const float4* p4 = (const float4*)partial;
        for (int cix = 0; cix < NCB; ++cix) {
            float4 x = p4[((size_t)cix * B + b) * (D / 4) + t];
            acc.x += x.x; acc.y += x.y; acc.z += x.z; acc.w += x.w;
        }
        acc.x *= inv; acc.y *= inv; acc.z *= inv; acc.w *= inv;
        ((float4*)(applied + (size_t)b * D))[t] = acc;
    }

    for (int s = t; s < S; s += 256)
        norm_w[(size_t)b * S + s] = u[(size_t)b * S + s] * inv;
}

extern "C" void kernel_launch(void* const* d_in, const int* in_sizes, int n_in,
                              void* d_out, int out_size, void* d_ws, size_t ws_size,
                              hipStream_t stream) {
    const float* enc   = (const float*)d_in[0];  // [S,B,D]
    const float* state = (const float*)d_in[1];  // [B,D]
    const float* prev  = (const float*)d_in[2];  // [B,S]
    const float* W     = (const float*)d_in[3];  // [D,D]
    const float* bias  = (const float*)d_in[4];  // [D]
    const float* cw    = (const float*)d_in[5];  // [K]
    const float* cb    = (const float*)d_in[6];  // [1]

    const int S = in_sizes[0] / in_sizes[1];   // 2048
    const int B = in_sizes[2] / S;             // 32
    const int D = in_sizes[1] / B;             // 512
    const int K = in_sizes[5];                 // 147

    float* out     = (float*)d_out;
    float* applied = out;                    // B*D
    float* norm_w  = out + (size_t)B * D;    // B*S

    const int NCB = 128;        // chunks per batch row (one wave each)
    const int CH = S / NCB;     // 16 s-rows per chunk

    float* ws      = (float*)d_ws;
    float* ns      = ws;                             // B*D
    float* adj     = ns + (size_t)B * D;             // B*S
    float* u       = adj + (size_t)B * S;            // B*S
    float* zbuf    = u + (size_t)B * S;              // NCB*B
    float* partial = zbuf + (size_t)NCB * B;         // NCB*B*D

    front_kernel<<<dim3(1 + S / 512, B), 512, 0, stream>>>(
        state, W, bias, prev, cw, cb, ns, adj, S, D, K);
    main_kernel<<<dim3(NCB / 4, B), 256, 0, stream>>>(
        enc, ns, adj, partial, zbuf, u, S, B, D, CH);
    combine_kernel<<<B, 256, 0, stream>>>(
        partial, zbuf, u, applied, norm_w, S, B, D, NCB);
}

// Round 5
// 251.002 us; speedup vs baseline: 1.0572x; 1.0572x over previous
//
#include <hip/hip_runtime.h>
#include <hip/hip_bf16.h>
#include <math.h>

// ---------------------------------------------------------------------------
// TimeAttender: S=2048, B=32, D=512, K=147
// out = concat(applied [B*D], norm_w [B*S])
//
// Math notes:
//  * prev_probs normalizer and softmax Z cancel in
//      norm_w = adj * exp(w) / sum_s(adj * exp(w))
//  * w is a cosine similarity in [-1,1] -> exp(w) in [0.37, 2.72]:
//    max-subtraction is unnecessary for fp32 safety, so the apply pass can
//    run single-pass (flash-style): e is read from HBM exactly ONCE.
//  * Round-4 lesson: wave-per-row (64 contiguous lanes -> one 1 KiB
//    coalesced segment per load) beats 16-lane-group layouts whose loads
//    fragment into 4 x 256 B segments and whose register arrays cut
//    occupancy. Keep this layout.
// ---------------------------------------------------------------------------

__device__ __forceinline__ float wave_sum(float v) {
    for (int off = 32; off; off >>= 1) v += __shfl_xor(v, off);
    return v;
}

// ---------------------------------------------------------------------------
// K1: grid (2 + S/256, B), block 256. Role split on blockIdx.x:
//   bx < 2      : attended[b, bx*256+t] = dot(state[b,:], W[d,:]) + bias[d]
//   bx >= 2     : adj[b, s] = relu(conv1d_same(prev[b,:], cw)[s] + cb0)
// ---------------------------------------------------------------------------
__global__ __launch_bounds__(256) void front_kernel(
    const float* __restrict__ state, const float* __restrict__ W,
    const float* __restrict__ bias, const float* __restrict__ prev,
    const float* __restrict__ cw, const float* __restrict__ cb,
    float* __restrict__ attended, float* __restrict__ adj,
    int S, int D, int K) {
    __shared__ __align__(16) float smem[1024];
    int b = blockIdx.y;
    int t = threadIdx.x;

    if (blockIdx.x < 2) {
        // ---- linear part ----
        if (t < D / 4)
            ((float4*)smem)[t] = ((const float4*)(state + (size_t)b * D))[t];
        __syncthreads();
        int d = blockIdx.x * 256 + t;
        const float4* Wrow = (const float4*)(W + (size_t)d * D);
        const float4* sv = (const float4*)smem;
        float acc = bias[d];
#pragma unroll 8
        for (int k = 0; k < 128; ++k) {
            float4 w4 = Wrow[k];
            float4 s4 = sv[k];
            acc += w4.x * s4.x + w4.y * s4.y + w4.z * s4.z + w4.w * s4.w;
        }
        attended[(size_t)b * D + d] = acc;
    } else {
        // ---- conv part ----
        int s0 = (blockIdx.x - 2) * 256;
        int pad = K / 2;
        int seglen = 256 + K - 1;
        float* seg = smem;            // seglen floats (<= 256+255)
        float* wk = smem + 512;       // K floats (<= 256)
        for (int i = t; i < seglen; i += 256) {
            int s = s0 - pad + i;
            seg[i] = (s >= 0 && s < S) ? prev[(size_t)b * S + s] : 0.f;
        }
        for (int j = t; j < K; j += 256) wk[j] = cw[j];
        __syncthreads();
        float y = cb[0];
        for (int j = 0; j < K; ++j) y += seg[t + j] * wk[j];
        adj[(size_t)b * S + s0 + t] = fmaxf(y, 0.f);
    }
}

// ---------------------------------------------------------------------------
// K2 (main, single e pass): grid (NCB/4, B), block 256 = 4 waves.
// Each WAVE owns chunk c = bx*4+wave of CH consecutive s for batch b:
//   - recompute ns[b,:] slice in registers from attended (2 KB, L2-hot)
//   - per row: w = dot(ns,e_row)/||e_row||; coef = adj*exp(w)
//              acc += coef*row; z += coef; u[b,s] = coef
//   - store acc -> partial[c][b][:], z -> zbuf[c][b]
// ---------------------------------------------------------------------------
__global__ __launch_bounds__(256) void main_kernel(
    const float* __restrict__ e, const float* __restrict__ attended,
    const float* __restrict__ adj, float* __restrict__ partial,
    float* __restrict__ zbuf, float* __restrict__ u,
    int S, int B, int D, int CH) {
    int wave = threadIdx.x >> 6;
    int lane = threadIdx.x & 63;
    int c = blockIdx.x * 4 + wave;
    int b = blockIdx.y;

    // ns slice for this lane (d = lane*4.. and d = 256+lane*4..)
    const float4* att4 = (const float4*)(attended + (size_t)b * D);
    float4 a0 = att4[lane];
    float4 a1 = att4[lane + 64];
    float asq = a0.x * a0.x + a0.y * a0.y + a0.z * a0.z + a0.w * a0.w
              + a1.x * a1.x + a1.y * a1.y + a1.z * a1.z + a1.w * a1.w;
    asq = wave_sum(asq);
    float an = sqrtf(asq);
    if (an == 0.f) an = 1e-10f;
    float ainv = 1.f / an;
    float4 ns0, ns1;
    ns0.x = a0.x * ainv; ns0.y = a0.y * ainv; ns0.z = a0.z * ainv; ns0.w = a0.w * ainv;
    ns1.x = a1.x * ainv; ns1.y = a1.y * ainv; ns1.z = a1.z * ainv; ns1.w = a1.w * ainv;

    float4 acc0 = {0.f, 0.f, 0.f, 0.f};
    float4 acc1 = {0.f, 0.f, 0.f, 0.f};
    float z = 0.f;

    int s0 = c * CH;
    const float4* row4 = (const float4*)(e + ((size_t)s0 * B + b) * D);
    size_t rstride = (size_t)B * D / 4;  // float4 stride between s rows

    float4 x0 = row4[lane];
    float4 x1 = row4[lane + 64];
    for (int i = 0; i < CH; ++i) {
        float4 nx0, nx1;
        if (i + 1 < CH) {
            nx0 = row4[rstride + lane];
            nx1 = row4[rstride + lane + 64];
        }
        float dot = x0.x * ns0.x + x0.y * ns0.y + x0.z * ns0.z + x0.w * ns0.w
                  + x1.x * ns1.x + x1.y * ns1.y + x1.z * ns1.z + x1.w * ns1.w;
        float sq  = x0.x * x0.x + x0.y * x0.y + x0.z * x0.z + x0.w * x0.w
                  + x1.x * x1.x + x1.y * x1.y + x1.z * x1.z + x1.w * x1.w;
        dot = wave_sum(dot);
        sq  = wave_sum(sq);
        float n = sqrtf(sq);
        if (n == 0.f) n = 1e-10f;
        float w = dot / n;
        float coef = adj[(size_t)b * S + s0 + i] * __expf(w);
        if (lane == 0) u[(size_t)b * S + s0 + i] = coef;
        acc0.x += coef * x0.x; acc0.y += coef * x0.y;
        acc0.z += coef * x0.z; acc0.w += coef * x0.w;
        acc1.x += coef * x1.x; acc1.y += coef * x1.y;
        acc1.z += coef * x1.z; acc1.w += coef * x1.w;
        z += coef;
        x0 = nx0; x1 = nx1;
        row4 += rstride;
    }

    float4* p4 = (float4*)(partial + ((size_t)c * B + b) * D);
    p4[lane] = acc0;
    p4[lane + 64] = acc1;
    if (lane == 0) zbuf[(size_t)c * B + b] = z;
}

// ---------------------------------------------------------------------------
// K3: grid B, block 256.
//   Z = sum_c zbuf[c][b];  applied[b,:] = sum_c partial[c][b][:] / Z;
//   norm_w[b,s] = u[b,s] / Z
// ---------------------------------------------------------------------------
__global__ __launch_bounds__(256) void combine_kernel(
    const float* __restrict__ partial, const float* __restrict__ zbuf,
    const float* __restrict__ u, float* __restrict__ applied,
    float* __restrict__ norm_w, int S, int B, int D, int NCB) {
    int b = blockIdx.x;
    int t = threadIdx.x;
    int lane = t & 63, wv = t >> 6;
    __shared__ float red[4];
    __shared__ float zsh;

    // Z reduce (threads 0..NCB-1 load one z each; NCB <= 256)
    float zt = (t < NCB) ? zbuf[(size_t)t * B + b] : 0.f;
    zt = wave_sum(zt);
    if (lane == 0) red[wv] = zt;
    __syncthreads();
    if (t == 0) zsh = 1.f / (red[0] + red[1] + red[2] + red[3]);
    __syncthreads();
    float inv = zsh;

    // applied: threads 0..127 each own one float4 of D
    if (t < D / 4) {
        float4 acc = {0.f, 0.f, 0.f, 0.f};
        const float4* p4 = (const float4*)partial;
        for (int cix = 0; cix < NCB; ++cix) {
            float4 x = p4[((size_t)cix * B + b) * (D / 4) + t];
            acc.x += x.x; acc.y += x.y; acc.z += x.z; acc.w += x.w;
        }
        acc.x *= inv; acc.y *= inv; acc.z *= inv; acc.w *= inv;
        ((float4*)(applied + (size_t)b * D))[t] = acc;
    }

    // norm_w
    for (int s = t; s < S; s += 256)
        norm_w[(size_t)b * S + s] = u[(size_t)b * S + s] * inv;
}

extern "C" void kernel_launch(void* const* d_in, const int* in_sizes, int n_in,
                              void* d_out, int out_size, void* d_ws, size_t ws_size,
                              hipStream_t stream) {
    const float* enc   = (const float*)d_in[0];  // [S,B,D]
    const float* state = (const float*)d_in[1];  // [B,D]
    const float* prev  = (const float*)d_in[2];  // [B,S]
    const float* W     = (const float*)d_in[3];  // [D,D]
    const float* bias  = (const float*)d_in[4];  // [D]
    const float* cw    = (const float*)d_in[5];  // [K]
    const float* cb    = (const float*)d_in[6];  // [1]

    const int S = in_sizes[0] / in_sizes[1];   // 2048
    const int B = in_sizes[2] / S;             // 32
    const int D = in_sizes[1] / B;             // 512
    const int K = in_sizes[5];                 // 147

    float* out     = (float*)d_out;
    float* applied = out;                    // B*D
    float* norm_w  = out + (size_t)B * D;    // B*S

    const int NCB = 128;        // chunks per batch row (one wave each)
    const int CH = S / NCB;     // 16 s-rows per chunk

    float* ws       = (float*)d_ws;
    float* attended = ws;                            // B*D
    float* adj      = attended + (size_t)B * D;      // B*S
    float* u        = adj + (size_t)B * S;           // B*S
    float* zbuf     = u + (size_t)B * S;             // NCB*B
    float* partial  = zbuf + (size_t)NCB * B;        // NCB*B*D

    front_kernel<<<dim3(2 + S / 256, B), 256, 0, stream>>>(
        state, W, bias, prev, cw, cb, attended, adj, S, D, K);
    main_kernel<<<dim3(NCB / 4, B), 256, 0, stream>>>(
        enc, attended, adj, partial, zbuf, u, S, B, D, CH);
    combine_kernel<<<B, 256, 0, stream>>>(
        partial, zbuf, u, applied, norm_w, S, B, D, NCB);
}